// Round 6
// baseline (384.538 us; speedup 1.0000x reference)
//
#include <hip/hip_runtime.h>
#include <stdint.h>

typedef unsigned short u16;
typedef __attribute__((ext_vector_type(8))) short bf16x8;   // 8 bf16 = 4 VGPRs
typedef __attribute__((ext_vector_type(4))) float f32x4;

#define NUM_B 2
#define SEQ   2048
#define SEQP  2080      // padded V row stride
#define NH    16
#define HD    128
#define EMB   2048      // NH*HD
#define N3    6144      // 3*EMB
#define MM    4096      // NUM_B*SEQ
#define QT    64        // flash q-rows per block (2 waves)
#define WQ    32        // flash q-rows per wave
#define KT    32        // flash keys per k-tile
#define NTILE (SEQ / KT)

// ---- GEMM tile params: 256x384, BK=64, 8 waves, 256 blocks = 1/CU, no tail ----
#define BM 256
#define BN 384
#define BK 64
#define NT_K (EMB / BK)   // 32 K-tiles, 16 iterations of 2

__device__ __forceinline__ u16 f2bf(float f) {
  union { float f; unsigned u; } c; c.f = f;
  return (u16)((c.u + 0x7FFFu + ((c.u >> 16) & 1u)) >> 16);   // RNE
}
__device__ __forceinline__ void async16(const void* g, void* l) {
  __builtin_amdgcn_global_load_lds(
      (const __attribute__((address_space(1))) void*)g,
      (__attribute__((address_space(3))) void*)l, 16, 0, 0);
}

#define GBAR()   asm volatile("s_barrier" ::: "memory")
#define WLGKM0() asm volatile("s_waitcnt lgkmcnt(0)" ::: "memory")

// ---------------- prep kernels ----------------

__global__ void k_cvt_bf16(const float* __restrict__ in, u16* __restrict__ out, int n4) {
  int i = blockIdx.x * blockDim.x + threadIdx.x;
  if (i >= n4) return;
  const float4 v = ((const float4*)in)[i];
  ushort4 o;
  o.x = f2bf(v.x); o.y = f2bf(v.y); o.z = f2bf(v.z); o.w = f2bf(v.w);
  ((ushort4*)out)[i] = o;
}

// W [EMB][N3] fp32 -> Wt [N3][EMB] bf16
__global__ void k_transpose_w(const float* __restrict__ W, u16* __restrict__ Wt) {
  __shared__ float t[32][33];
  int n0 = blockIdx.x * 32, k0 = blockIdx.y * 32;
  int tx = threadIdx.x, ty = threadIdx.y;
  #pragma unroll
  for (int i = ty; i < 32; i += 8)
    t[i][tx] = W[(size_t)(k0 + i) * N3 + n0 + tx];
  __syncthreads();
  #pragma unroll
  for (int i = ty; i < 32; i += 8)
    Wt[(size_t)(n0 + i) * EMB + k0 + tx] = f2bf(t[tx][i]);
}

// sincos table for t = s*HD + d; double-precision sincos matches numpy fp32 tables
__global__ void k_sincos(float2* __restrict__ tab) {
  int i = blockIdx.x * blockDim.x + threadIdx.x;   // 0 .. SEQ*HD-1
  double t = (double)i;
  tab[i] = make_float2((float)cos(t), (float)sin(t));
}

// ---------------- QKV GEMM: 256x384 tile, 4-phase/K-tile, zero grid tail ----------------
// R4 post-mortem: 384-block grid -> 1.5 rounds at 1 block/CU (x0.75), and the
// q0 phase bundled 12/16 ds_reads (R2-style imbalance). Fix: 256x384 tiles ->
// 16x16 = 256 blocks = exactly 1/CU (no tail); phases split on (kk, m-half):
//   p = kk*2 + mh; reads: bfr[6] at mh==0 phases (kk-half) + af[4] per phase
//   -> 10/4/10/4 b128 vs 24 MFMA per phase (vs 16/4/4/4 vs 16 before).
// Per-wave output 128x96 (8mf x 6nf): 0.29 b128/MFMA.
// LDS: lsA[2][256*64] 64 KB + lsB[2][384*64] 96 KB = 160 KB (gfx950 max), 1/CU.
// Staging per iter (t0,t1; A/B buf = t&1; B = 3 units of 128 rows):
//   hp0.p0: A(t1,0) B(t1,1)    hp0.p1: A(t1,1) B(t1,2)   hp0.p2: -
//   hp0.p3: B(t0+2,0) ; vmcnt(2) -> lands A(t1)+B(t1) (incl. B(t1,0) staged
//           at prev iter hp1.p3), keeps B(t0+2,0)
//   hp1.p0: A(t0+2,0) B(t0+2,1)  hp1.p1: A(t0+2,1) B(t0+2,2)  hp1.p2: -
//   hp1.p3: B(t1+2,0) ; vmcnt(2) -> lands A(t0+2)+B(t0+2), keeps B(t1+2,0)
// Hazards: every stage target's last ds_read retired >=1 phase-end-barrier
// before the stage issue (B(t) last read at p2 = kk1 bfr load -> B(t+2) unit 0
// earliest p3; A(t) last read at p3 -> A(t+2) earliest next-half p0). Issue->
// wait distance >= 2 phases (~2200 cyc) > 900 cyc HBM. vmcnt never 0 in loop.
// Swizzle (T2, 0-conflict R1-R4): slot quad = quad ^ (row&7) on per-lane
// GLOBAL source (LDS dest linear) + on the ds_read quad; frag rows all have
// row&7 == lq&7 so qsw[kk] = ((kk*4+lr)^(lq&7))*8.
// RoPE/qkv mapping (BN=384 = 3 whole heads; n0 % 128 == 0, but 384 does not
// divide 2048 so q/k/v varies per head WITHIN a tile): pair index pi = 3*wc+pl
// (pl=0..2), head j = pi>>2, off = (pi&3)*16; nf = 2*pl+half -> tile col
// o = j*128 + off + half*64 + lq. Each wave holds both halves of its 3
// (d, d+64) pairs; bijective over 384 cols; w/h computed per head-group.
__global__ __launch_bounds__(512, 1) void k_gemm_qkv(
    const u16* __restrict__ xb, const u16* __restrict__ wt,
    const float* __restrict__ bias, const float2* __restrict__ tab,
    u16* __restrict__ qb, u16* __restrict__ kb, u16* __restrict__ vbt)
{
  __shared__ __align__(16) u16 lsA[2][BM * BK];   // 32 KB x2
  __shared__ __align__(16) u16 lsB[2][BN * BK];   // 48 KB x2  (160 KB total)
  const int tid = threadIdx.x;            // 0..511
  const int wave = tid >> 6, lane = tid & 63;
  const int lq = lane & 15, lr = lane >> 4;
  const int wr = wave >> 2, wc = wave & 3;
  const int m0 = blockIdx.y * BM, n0 = blockIdx.x * BN;

  auto stA = [&](int t, int half) {       // 128 rows x 64: 2 loads/thread, 16 KB
    const int kt = t * BK;
    #pragma unroll
    for (int ii = 0; ii < 2; ++ii) {
      int s = ii * 512 + tid;             // 16B slot 0..1023 within half
      int row = s >> 3, gq = (s & 7) ^ (row & 7);
      async16(xb + (size_t)(m0 + half * 128 + row) * EMB + kt + gq * 8,
              &lsA[t & 1][half * 8192 + s * 8]);
    }
  };
  auto stB = [&](int t, int third) {      // 128 rows x 64: 2 loads/thread, 16 KB
    const int kt = t * BK;
    #pragma unroll
    for (int ii = 0; ii < 2; ++ii) {
      int s = ii * 512 + tid;
      int row = s >> 3, gq = (s & 7) ^ (row & 7);
      async16(wt + (size_t)(n0 + third * 128 + row) * EMB + kt + gq * 8,
              &lsB[t & 1][third * 8192 + s * 8]);
    }
  };

  f32x4 acc[8][6];
  #pragma unroll
  for (int i = 0; i < 8; ++i)
    #pragma unroll
    for (int j = 0; j < 6; ++j)
      acc[i][j] = f32x4{0.f, 0.f, 0.f, 0.f};

  // per-lane LDS read offsets (u16 units)
  int rbase[6];
  #pragma unroll
  for (int nf = 0; nf < 6; ++nf) {
    int pi = 3 * wc + (nf >> 1);
    int o = (pi >> 2) * 128 + (pi & 3) * 16 + (nf & 1) * 64;
    rbase[nf] = (o + lq) * BK;
  }
  const int aRow0 = (wr * 128 + lq) * BK;
  int qsw[2];
  qsw[0] = ((0 + lr) ^ (lq & 7)) * 8;
  qsw[1] = ((4 + lr) ^ (lq & 7)) * 8;

  // prologue: A(0) B(0) B(1,0) = 12 loads; vmcnt(2) -> A(0)+B(0) landed
  stA(0, 0); stA(0, 1); stB(0, 0); stB(0, 1); stB(0, 2); stB(1, 0);
  asm volatile("s_waitcnt vmcnt(2)" ::: "memory");
  GBAR();

  for (int ti = 0; ti < NT_K / 2; ++ti) {
    const int t0 = 2 * ti, t1 = t0 + 1;
    const bool nl = (ti < NT_K / 2 - 1);

    #pragma unroll
    for (int hp = 0; hp < 2; ++hp) {      // hp=0: tile t0 (buf0), hp=1: t1 (buf1)
      const u16* Ap = lsA[hp];
      const u16* Bp = lsB[hp];
      bf16x8 bfr[6];

      #pragma unroll
      for (int p = 0; p < 4; ++p) {
        const int kk = p >> 1, mh = p & 1;
        // ---- ds_read register subtiles ----
        if (mh == 0) {
          #pragma unroll
          for (int nf = 0; nf < 6; ++nf)
            bfr[nf] = *(const bf16x8*)(Bp + rbase[nf] + qsw[kk]);
        }
        bf16x8 af[4];
        #pragma unroll
        for (int m4 = 0; m4 < 4; ++m4)
          af[m4] = *(const bf16x8*)(Ap + aRow0 + ((mh * 4 + m4) * 16) * BK + qsw[kk]);

        // ---- stage schedule ----
        if (hp == 0) {
          if      (p == 0) { stA(t1, 0); stB(t1, 1); }
          else if (p == 1) { stA(t1, 1); stB(t1, 2); }
          else if (p == 3) {
            if (nl) {
              stB(t0 + 2, 0);
              asm volatile("s_waitcnt vmcnt(2)" ::: "memory");  // lands A(t1)+B(t1)
            } else {
              asm volatile("s_waitcnt vmcnt(0)" ::: "memory");  // drain for final tile
            }
          }
        } else {
          if (nl) {
            if      (p == 0) { stA(t0 + 2, 0); stB(t0 + 2, 1); }
            else if (p == 1) { stA(t0 + 2, 1); stB(t0 + 2, 2); }
            else if (p == 3) {
              stB(t1 + 2, 0);
              asm volatile("s_waitcnt vmcnt(2)" ::: "memory");  // lands A(t0+2)+B(t0+2)
            }
          }
        }
        if (mh == 0) asm volatile("s_waitcnt lgkmcnt(4)" ::: "memory");  // partial drain, 10-read phase

        GBAR();
        WLGKM0();
        __builtin_amdgcn_s_setprio(1);
        #pragma unroll
        for (int m4 = 0; m4 < 4; ++m4)
          #pragma unroll
          for (int nf = 0; nf < 6; ++nf)
            acc[mh * 4 + m4][nf] = __builtin_amdgcn_mfma_f32_16x16x32_bf16(
                af[m4], bfr[nf], acc[mh * 4 + m4][nf], 0, 0, 0);
        __builtin_amdgcn_s_setprio(0);
        GBAR();
      }
    }
  }

  // ---------------- epilogue (fused bias + RoPE / V-transpose, per head-group) ----------------
  const int m0w = m0 + wr * 128;
  #pragma unroll
  for (int pl = 0; pl < 3; ++pl) {
    const int pi = 3 * wc + pl;
    const int j = pi >> 2;                 // head within tile (0..2)
    const int H = (n0 >> 7) + j;           // absolute head index (0..47)
    const int w = H >> 4;                  // 0=q, 1=k, 2=v
    const int h = H & 15;
    const int poff = (pi & 3) * 16;
    const float b1 = bias[n0 + j * 128 + poff + lq];
    const float b2 = bias[n0 + j * 128 + poff + 64 + lq];

    if (w == 2) {
      // V: transpose to [B,H,D,SEQP], 4 consecutive s per 8B store
      #pragma unroll
      for (int mf = 0; mf < 8; ++mf) {
        int mg0 = m0w + mf * 16 + lr * 4;
        int b = mg0 >> 11, s0 = mg0 & 2047;
        ushort4 pk;
        pk.x = f2bf(acc[mf][2 * pl][0] + b1);
        pk.y = f2bf(acc[mf][2 * pl][1] + b1);
        pk.z = f2bf(acc[mf][2 * pl][2] + b1);
        pk.w = f2bf(acc[mf][2 * pl][3] + b1);
        *(ushort4*)(vbt + ((size_t)(b * NH + h) * HD + poff + lq) * SEQP + s0) = pk;
        pk.x = f2bf(acc[mf][2 * pl + 1][0] + b2);
        pk.y = f2bf(acc[mf][2 * pl + 1][1] + b2);
        pk.z = f2bf(acc[mf][2 * pl + 1][2] + b2);
        pk.w = f2bf(acc[mf][2 * pl + 1][3] + b2);
        *(ushort4*)(vbt + ((size_t)(b * NH + h) * HD + poff + 64 + lq) * SEQP + s0) = pk;
      }
    } else {
      u16* basep = (w == 0) ? qb : kb;
      const float qs = (w == 0) ? 0.12751569843736827f : 1.0f;  // log2(e)/sqrt(128) into q
      #pragma unroll
      for (int mf = 0; mf < 8; ++mf)
        #pragma unroll
        for (int r = 0; r < 4; ++r) {
          int mg = m0w + mf * 16 + lr * 4 + r;
          int b = mg >> 11, s = mg & 2047;
          u16* dst = basep + ((size_t)(b * NH + h) * SEQ + s) * HD;
          int d1 = poff + lq;                      // in [0,64); partner d1+64
          float c1 = acc[mf][2 * pl][r]     + b1;
          float c2 = acc[mf][2 * pl + 1][r] + b2;
          float2 s1 = tab[s * HD + d1];
          float2 s2 = tab[s * HD + d1 + 64];
          dst[d1]      = f2bf((c1 * s1.x - c2 * s1.y) * qs);
          dst[d1 + 64] = f2bf((c2 * s2.x + c1 * s2.y) * qs);
        }
    }
  }
}

// ---------------- flash attention (unchanged; round-4 structure + XCD-aware remap) ----------------
__global__ __launch_bounds__(128, 2) void k_flash(
    const u16* __restrict__ qb, const u16* __restrict__ kb,
    const u16* __restrict__ vbt, float* __restrict__ out)
{
  __shared__ __align__(16) u16 lsK[2][KT * HD];   // [key][d] 16B-grp ^= key&7    (8 KB x2)
  __shared__ __align__(16) u16 lsV[2][HD * KT];   // [d][key] 16B-grp ^= (d>>1)&3 (8 KB x2)
  __shared__ __align__(16) u16 lsP[2][WQ * KT];   // per-wave [qrow][key], 8B-grp ^= row&6

  const int tid = threadIdx.x;            // 0..127
  const int wave = tid >> 6, lane = tid & 63;
  const int lq = lane & 15, lr = lane >> 4;
  const int i = blockIdx.x;               // 0..1023
  const int xcd = i & 7, j = i >> 3;      // j: 0..127
  const int bh = xcd * 4 + (j >> 5);      // 4 heads per XCD
  const int q0 = (j & 31) * QT;
  const u16* Qg = qb + ((size_t)bh * SEQ + q0 + wave * WQ) * HD;
  const u16* Kg = kb + (size_t)bh * SEQ * HD;
  const u16* Vg = vbt + (size_t)bh * HD * SEQP;

  auto stage = [&](int tile, int buf) {
    const int k0 = tile * KT;
    #pragma unroll
    for (int ii = 0; ii < 4; ++ii) {
      int c = tid + ii * 128;
      int key = c >> 4, grp = c & 15;
      async16(Kg + (size_t)(k0 + key) * HD + ((grp ^ (key & 7)) * 8), lsK[buf] + c * 8);
    }
    #pragma unroll
    for (int ii = 0; ii < 4; ++ii) {
      int c = tid + ii * 128;
      int d = c >> 2, g2 = c & 3;
      async16(Vg + (size_t)d * SEQP + k0 + ((g2 ^ ((d >> 1) & 3)) * 8), lsV[buf] + c * 8);
    }
  };

  stage(0, 0);

  bf16x8 qf[2][4];
  #pragma unroll
  for (int qq = 0; qq < 2; ++qq)
    #pragma unroll
    for (int ks = 0; ks < 4; ++ks)
      qf[qq][ks] = *(const bf16x8*)(Qg + (size_t)(qq * 16 + lq) * HD + ks * 32 + lr * 8);

  f32x4 acc_o[2][8];
  float lsum[2] = {0.f, 0.f};
  #pragma unroll
  for (int mb = 0; mb < 2; ++mb)
    #pragma unroll
    for (int nb = 0; nb < 8; ++nb) acc_o[mb][nb] = f32x4{0.f, 0.f, 0.f, 0.f};

  for (int t = 0; t < NTILE; ++t) {
    const int p = t & 1;
    __syncthreads();                 // drains stage(t); all waves done with buf 1-p
    if (t + 1 < NTILE) stage(t + 1, 1 - p);

    // S^T = K Q^T : 32 keys x 32 q-rows per wave
    f32x4 sacc[2][2];
    #pragma unroll
    for (int kbi = 0; kbi < 2; ++kbi)
      #pragma unroll
      for (int qq = 0; qq < 2; ++qq) sacc[kbi][qq] = f32x4{0.f, 0.f, 0.f, 0.f};
    #pragma unroll
    for (int ks = 0; ks < 4; ++ks) {
      bf16x8 kf[2];
      #pragma unroll
      for (int kbi = 0; kbi < 2; ++kbi) {
        int key = kbi * 16 + lq;
        int g = (ks * 4 + lr) ^ (key & 7);
        kf[kbi] = *(const bf16x8*)(lsK[p] + key * HD + g * 8);
      }
      #pragma unroll
      for (int kbi = 0; kbi < 2; ++kbi)
        #pragma unroll
        for (int qq = 0; qq < 2; ++qq)
          sacc[kbi][qq] = __builtin_amdgcn_mfma_f32_16x16x32_bf16(kf[kbi], qf[qq][ks], sacc[kbi][qq], 0, 0, 0);
    }

    // P = exp2(S) (log2e folded into q); packed b64 writes (4 consecutive keys/lane)
    #pragma unroll
    for (int kbi = 0; kbi < 2; ++kbi)
      #pragma unroll
      for (int qq = 0; qq < 2; ++qq) {
        float p0 = __builtin_amdgcn_exp2f(sacc[kbi][qq][0]);
        float p1 = __builtin_amdgcn_exp2f(sacc[kbi][qq][1]);
        float p2 = __builtin_amdgcn_exp2f(sacc[kbi][qq][2]);
        float p3 = __builtin_amdgcn_exp2f(sacc[kbi][qq][3]);
        lsum[qq] += (p0 + p1) + (p2 + p3);
        int row = qq * 16 + lq;
        int g = kbi * 4 + lr;
        int gp = g ^ (row & 6);
        uint2 pk;
        pk.x = (uint32_t)f2bf(p0) | ((uint32_t)f2bf(p1) << 16);
        pk.y = (uint32_t)f2bf(p2) | ((uint32_t)f2bf(p3) << 16);
        *(uint2*)(lsP[wave] + row * KT + gp * 4) = pk;
      }

    // O += P V
    bf16x8 ap[2];
    #pragma unroll
    for (int mb = 0; mb < 2; ++mb) {
      int row = mb * 16 + lq;
      int gp = (2 * lr) ^ (row & 6);
      ap[mb] = *(const bf16x8*)(lsP[wave] + row * KT + gp * 4);
    }
    #pragma unroll
    for (int nb = 0; nb < 8; ++nb) {
      int d = nb * 16 + lq;
      int g2 = lr ^ ((d >> 1) & 3);
      bf16x8 bv = *(const bf16x8*)(lsV[p] + d * KT + g2 * 8);
      #pragma unroll
      for (int mb = 0; mb < 2; ++mb)
        acc_o[mb][nb] = __builtin_amdgcn_mfma_f32_16x16x32_bf16(ap[mb], bv[0] == bv[0] ? bv : bv, acc_o[mb][nb], 0, 0, 0);
    }
  }

  float inv[2];
  #pragma unroll
  for (int qq = 0; qq < 2; ++qq) {
    float s = lsum[qq];
    s += __shfl_xor(s, 16);
    s += __shfl_xor(s, 32);
    inv[qq] = 1.0f / s;
  }
  const int b = bh >> 4, h = bh & 15;
  #pragma unroll
  for (int mb = 0; mb < 2; ++mb)
    #pragma unroll
    for (int r = 0; r < 4; ++r) {
      float iv = __shfl(inv[mb], lr * 4 + r);
      int row = wave * WQ + mb * 16 + lr * 4 + r;
      int sq = q0 + row;
      float* op = out + (((size_t)b * SEQ + sq) * NH + h) * HD;
      #pragma unroll
      for (int nb = 0; nb < 8; ++nb)
        op[nb * 16 + lq] = acc_o[mb][nb][r] * iv;
    }
}

// ---------------- launch ----------------

extern "C" void kernel_launch(void* const* d_in, const int* in_sizes, int n_in,
                              void* d_out, int out_size, void* d_ws, size_t ws_size,
                              hipStream_t stream) {
  (void)in_sizes; (void)n_in; (void)out_size; (void)ws_size;
  const float* x    = (const float*)d_in[0];
  const float* W    = (const float*)d_in[1];
  const float* bias = (const float*)d_in[2];
  float* out = (float*)d_out;

  char* p = (char*)d_ws;
  u16* xb  = (u16*)p;  p += (size_t)MM * EMB * 2;                     // 16.8 MB
  u16* wt  = (u16*)p;  p += (size_t)N3 * EMB * 2;                     // 25.2 MB
  u16* qb  = (u16*)p;  p += (size_t)NUM_B * NH * SEQ * HD * 2;        // 16.8 MB
  u16* kb  = (u16*)p;  p += (size_t)NUM_B * NH * SEQ * HD * 2;        // 16.8 MB
  u16* vbt = (u16*)p;  p += (size_t)NUM_B * NH * HD * SEQP * 2;       // 17.0 MB
  float2* tab = (float2*)p;                                           // 2.1 MB

  k_cvt_bf16<<<(MM * EMB / 4 + 255) / 256, 256, 0, stream>>>(x, xb, MM * EMB / 4);
  k_transpose_w<<<dim3(N3 / 32, EMB / 32), dim3(32, 8), 0, stream>>>(W, wt);
  k_sincos<<<(SEQ * HD) / 256, 256, 0, stream>>>(tab);
  k_gemm_qkv<<<dim3(N3 / BN, MM / BM), 512, 0, stream>>>(xb, wt, bias, tab, qb, kb, vbt);
  k_flash<<<SEQ / QT * NUM_B * NH, 128, 0, stream>>>(qb, kb, vbt, out);
}

// Round 7
// 253.154 us; speedup vs baseline: 1.5190x; 1.5190x over previous
//
#include <hip/hip_runtime.h>
#include <stdint.h>

typedef unsigned short u16;
typedef __attribute__((ext_vector_type(8))) short bf16x8;   // 8 bf16 = 4 VGPRs
typedef __attribute__((ext_vector_type(4))) float f32x4;

#define NUM_B 2
#define SEQ   2048
#define SEQP  2080      // padded V row stride
#define NH    16
#define HD    128
#define EMB   2048      // NH*HD
#define N3    6144      // 3*EMB
#define MM    4096      // NUM_B*SEQ
#define QT    64        // flash q-rows per block (2 waves)
#define WQ    32        // flash q-rows per wave
#define KT    32        // flash keys per k-tile
#define NTILE (SEQ / KT)

// ---- GEMM tile params: m201-geometry 256x256, BK=64, 8 waves ----
#define BM 256
#define BN 256
#define BK 64
#define NT_K (EMB / BK)   // 32 K-tiles, 16 iterations of 2

__device__ __forceinline__ u16 f2bf(float f) {
  union { float f; unsigned u; } c; c.f = f;
  return (u16)((c.u + 0x7FFFu + ((c.u >> 16) & 1u)) >> 16);   // RNE
}
__device__ __forceinline__ void async16(const void* g, void* l) {
  __builtin_amdgcn_global_load_lds(
      (const __attribute__((address_space(1))) void*)g,
      (__attribute__((address_space(3))) void*)l, 16, 0, 0);
}

#define GBAR()   asm volatile("s_barrier" ::: "memory")
#define WLGKM0() asm volatile("s_waitcnt lgkmcnt(0)" ::: "memory")

// ---------------- prep kernels ----------------

__global__ void k_cvt_bf16(const float* __restrict__ in, u16* __restrict__ out, int n4) {
  int i = blockIdx.x * blockDim.x + threadIdx.x;
  if (i >= n4) return;
  const float4 v = ((const float4*)in)[i];
  ushort4 o;
  o.x = f2bf(v.x); o.y = f2bf(v.y); o.z = f2bf(v.z); o.w = f2bf(v.w);
  ((ushort4*)out)[i] = o;
}

// W [EMB][N3] fp32 -> Wt [N3][EMB] bf16
__global__ void k_transpose_w(const float* __restrict__ W, u16* __restrict__ Wt) {
  __shared__ float t[32][33];
  int n0 = blockIdx.x * 32, k0 = blockIdx.y * 32;
  int tx = threadIdx.x, ty = threadIdx.y;
  #pragma unroll
  for (int i = ty; i < 32; i += 8)
    t[i][tx] = W[(size_t)(k0 + i) * N3 + n0 + tx];
  __syncthreads();
  #pragma unroll
  for (int i = ty; i < 32; i += 8)
    Wt[(size_t)(n0 + i) * EMB + k0 + tx] = f2bf(t[tx][i]);
}

// sincos table for t = s*HD + d; double-precision sincos matches numpy fp32 tables
__global__ void k_sincos(float2* __restrict__ tab) {
  int i = blockIdx.x * blockDim.x + threadIdx.x;   // 0 .. SEQ*HD-1
  double t = (double)i;
  tab[i] = make_float2((float)cos(t), (float)sin(t));
}

// ---------------- QKV GEMM: 256x256, 8 waves, balanced (kk,mh) 4-phase ----------------
// R6 post-mortem: 256x384 -> acc[8][6]=192 regs/wave -> scratch spill (WRITE
// 50->255 MB, 15% MfmaUtil). Constraint: per-wave acc <= 128 f32 -> back to
// the proven 256x256 / acc[8][4] geometry (R4: no spill, 134.8 us).
// R4's residual flaw: q0 phase bundled 12/24 ds_reads. Fix: phases keyed
// (kk, mh) -> reads 8/4/8/4 vs 16 MFMA each:
//   P0(kk0,mh0): bfr[4][kk0] + af[0-3][kk0] (8 rd)  P1(kk0,mh1): af[4-7][kk0] (4)
//   P2(kk1,mh0): bfr[4][kk1] + af[0-3][kk1] (8)     P3(kk1,mh1): af[4-7][kk1] (4)
// Per-element accumulation order kk0->kk1 unchanged -> bit-identical.
// Staging (2 K-tiles per iter; buf = t&1; 2 async16-calls per slot):
//   hp0: P0 stA(t1,0)  P1 stA(t1,1)  P3 stB(t0+2,0)+stB(t0+2,1) ; vmcnt(4)
//        (queue: B(t1)4 A(t1)4 B(t0+2)4 -> lands tile t1, keeps B(t0+2))
//   hp1: P0 stA(t0+2,0) P1 stA(t0+2,1) P3 stB(t1+2,0)+stB(t1+2,1) ; vmcnt(4)
//        (queue: B(t0+2)4 A(t0+2)4 B(t1+2)4 -> lands t0+2, keeps B(t1+2))
// B staged only at P3 (P2's bfr reads retired at P2's WLGKM0, before P2 end
// barrier -> no read/overwrite race; staging at P2 would race its own bfr).
// vmcnt never 0 except last pair. Phase: reads; stage; [lgkmcnt(4) if 8-rd];
// GBAR; lgkmcnt(0); setprio(1); 16 MFMA; setprio(0); GBAR.
// Swizzle (T2, 0-conflict R1-R6): slot quad = quad ^ (row&7) on per-lane
// GLOBAL source (LDS dest linear) + on ds_read quad; frag rows have
// row&7 == lq&7 so qsw[kk] = ((kk*4+lr)^(lq&7))*8.
// RoPE-pair N-remap (verified R4): wave wc, frag nf -> within-head
// d = (2*(wc&1)+(nf>>1))*16 + (nf&1)*64 + lq, head = wc>>1.
__global__ __launch_bounds__(512, 2) void k_gemm_qkv(
    const u16* __restrict__ xb, const u16* __restrict__ wt,
    const float* __restrict__ bias, const float2* __restrict__ tab,
    u16* __restrict__ qb, u16* __restrict__ kb, u16* __restrict__ vbt)
{
  __shared__ __align__(16) u16 lsA[2][BM * BK];   // 32 KB x2
  __shared__ __align__(16) u16 lsB[2][BN * BK];   // 32 KB x2  (128 KB total)
  const int tid = threadIdx.x;            // 0..511
  const int wave = tid >> 6, lane = tid & 63;
  const int lq = lane & 15, lr = lane >> 4;
  const int wr = wave >> 2, wc = wave & 3;
  const int m0 = blockIdx.y * BM, n0 = blockIdx.x * BN;

  auto stA = [&](int t, int half) {       // one half-tile: 2 loads/thread, 16 KB
    const int kt = t * BK;
    #pragma unroll
    for (int ii = 0; ii < 2; ++ii) {
      int s = ii * 512 + tid;             // 16B slot 0..1023 within half
      int row = s >> 3, gq = (s & 7) ^ (row & 7);
      async16(xb + (size_t)(m0 + half * 128 + row) * EMB + kt + gq * 8,
              &lsA[t & 1][half * 8192 + s * 8]);
    }
  };
  auto stB = [&](int t, int half) {
    const int kt = t * BK;
    #pragma unroll
    for (int ii = 0; ii < 2; ++ii) {
      int s = ii * 512 + tid;
      int row = s >> 3, gq = (s & 7) ^ (row & 7);
      async16(wt + (size_t)(n0 + half * 128 + row) * EMB + kt + gq * 8,
              &lsB[t & 1][half * 8192 + s * 8]);
    }
  };

  f32x4 acc[8][4];
  #pragma unroll
  for (int i = 0; i < 8; ++i)
    #pragma unroll
    for (int j = 0; j < 4; ++j)
      acc[i][j] = f32x4{0.f, 0.f, 0.f, 0.f};

  // per-lane LDS read offsets (u16 units)
  int rbase[4];
  #pragma unroll
  for (int nf = 0; nf < 4; ++nf)
    rbase[nf] = ((wc >> 1) * 128 + (2 * (wc & 1) + (nf >> 1)) * 16 + (nf & 1) * 64 + lq) * BK;
  const int aRow0 = (wr * 128 + lq) * BK;
  int qsw[2];
  qsw[0] = ((0 + lr) ^ (lq & 7)) * 8;
  qsw[1] = ((4 + lr) ^ (lq & 7)) * 8;

  // prologue: A(0) B(0) B(1) = 12 loads; vmcnt(4) -> A(0)+B(0) landed, B(1) in flight
  stA(0, 0); stA(0, 1); stB(0, 0); stB(0, 1); stB(1, 0); stB(1, 1);
  asm volatile("s_waitcnt vmcnt(4)" ::: "memory");
  GBAR();

  for (int ti = 0; ti < NT_K / 2; ++ti) {
    const int t0 = 2 * ti, t1 = t0 + 1;
    const bool nl = (ti < NT_K / 2 - 1);

    #pragma unroll
    for (int hp = 0; hp < 2; ++hp) {      // hp=0: tile t0 (buf0), hp=1: t1 (buf1)
      const u16* Ap = lsA[hp];
      const u16* Bp = lsB[hp];

      #pragma unroll
      for (int p = 0; p < 4; ++p) {
        const int kk = p >> 1, mh = p & 1;
        // ---- ds_read register subtiles ----
        bf16x8 bfr[4];
        if (mh == 0) {
          #pragma unroll
          for (int nf = 0; nf < 4; ++nf)
            bfr[nf] = *(const bf16x8*)(Bp + rbase[nf] + qsw[kk]);
        }
        bf16x8 af[4];
        #pragma unroll
        for (int m4 = 0; m4 < 4; ++m4)
          af[m4] = *(const bf16x8*)(Ap + aRow0 + ((mh * 4 + m4) * 16) * BK + qsw[kk]);

        // ---- stage schedule (A at P0/P1, B bunched at P3, counted vmcnt) ----
        if (hp == 0) {
          if      (p == 0) stA(t1, 0);
          else if (p == 1) stA(t1, 1);
          else if (p == 3) {
            if (nl) {
              stB(t0 + 2, 0); stB(t0 + 2, 1);
              asm volatile("s_waitcnt vmcnt(4)" ::: "memory");  // lands A(t1)+B(t1)
            } else {
              asm volatile("s_waitcnt vmcnt(0)" ::: "memory");  // drain for final tile
            }
          }
        } else {
          if (nl) {
            if      (p == 0) stA(t0 + 2, 0);
            else if (p == 1) stA(t0 + 2, 1);
            else if (p == 3) {
              stB(t1 + 2, 0); stB(t1 + 2, 1);
              asm volatile("s_waitcnt vmcnt(4)" ::: "memory");  // lands tile t0+2
            }
          }
        }
        if (mh == 0) asm volatile("s_waitcnt lgkmcnt(4)" ::: "memory");  // partial drain, 8-read phase

        GBAR();
        WLGKM0();
        __builtin_amdgcn_s_setprio(1);
        // bfr persists across the mh==1 phase in regs (read at mh==0 of this kk)
        static bf16x8 bfr_keep[4];  // (never used; placeholder comment-free)
        (void)bfr_keep;
        #pragma unroll
        for (int m4 = 0; m4 < 4; ++m4)
          #pragma unroll
          for (int nf = 0; nf < 4; ++nf)
            acc[mh * 4 + m4][nf] = __builtin_amdgcn_mfma_f32_16x16x32_bf16(
                af[m4], bfr[nf], acc[mh * 4 + m4][nf], 0, 0, 0);
        __builtin_amdgcn_s_setprio(0);
        GBAR();
      }
    }
  }

  // ---------------- epilogue (fused bias + RoPE / V-transpose; verified R4) ----------------
  const int w = n0 >> 11;                  // 0=q, 1=k, 2=v (BN=256 divides 2048)
  const int h = ((n0 & 2047) >> 7) + (wc >> 1);
  float bb[4];
  int dloc[4];
  #pragma unroll
  for (int nf = 0; nf < 4; ++nf) {
    dloc[nf] = (2 * (wc & 1) + (nf >> 1)) * 16 + (nf & 1) * 64 + lq;   // d within head
    bb[nf] = bias[n0 + (wc >> 1) * 128 + dloc[nf]];
  }

  if (w == 2) {
    // V: transpose to [B,H,D,SEQP], 4 consecutive s per 8B store
    #pragma unroll
    for (int mf = 0; mf < 8; ++mf) {
      int mg0 = m0 + wr * 128 + mf * 16 + lr * 4;
      int b = mg0 >> 11, s0 = mg0 & 2047;
      #pragma unroll
      for (int nf = 0; nf < 4; ++nf) {
        int d = dloc[nf];
        ushort4 pk;
        pk.x = f2bf(acc[mf][nf][0] + bb[nf]);
        pk.y = f2bf(acc[mf][nf][1] + bb[nf]);
        pk.z = f2bf(acc[mf][nf][2] + bb[nf]);
        pk.w = f2bf(acc[mf][nf][3] + bb[nf]);
        *(ushort4*)(vbt + ((size_t)(b * NH + h) * HD + d) * SEQP + s0) = pk;
      }
    }
  } else {
    u16* basep = (w == 0) ? qb : kb;
    const float qs = (w == 0) ? 0.12751569843736827f : 1.0f;  // log2(e)/sqrt(128) into q
    #pragma unroll
    for (int mf = 0; mf < 8; ++mf)
      #pragma unroll
      for (int r = 0; r < 4; ++r) {
        int mg = m0 + wr * 128 + mf * 16 + lr * 4 + r;
        int b = mg >> 11, s = mg & 2047;
        u16* dst = basep + ((size_t)(b * NH + h) * SEQ + s) * HD;
        #pragma unroll
        for (int pl = 0; pl < 2; ++pl) {
          int d1 = (2 * (wc & 1) + pl) * 16 + lq;      // in [0,64); partner d1+64
          float c1 = acc[mf][2 * pl][r]     + bb[2 * pl];
          float c2 = acc[mf][2 * pl + 1][r] + bb[2 * pl + 1];
          float2 s1 = tab[s * HD + d1];
          float2 s2 = tab[s * HD + d1 + 64];
          dst[d1]      = f2bf((c1 * s1.x - c2 * s1.y) * qs);
          dst[d1 + 64] = f2bf((c2 * s2.x + c1 * s2.y) * qs);
        }
      }
  }
}

// ---------------- flash attention (unchanged; round-4 structure + XCD-aware remap) ----------------
__global__ __launch_bounds__(128, 2) void k_flash(
    const u16* __restrict__ qb, const u16* __restrict__ kb,
    const u16* __restrict__ vbt, float* __restrict__ out)
{
  __shared__ __align__(16) u16 lsK[2][KT * HD];   // [key][d] 16B-grp ^= key&7    (8 KB x2)
  __shared__ __align__(16) u16 lsV[2][HD * KT];   // [d][key] 16B-grp ^= (d>>1)&3 (8 KB x2)
  __shared__ __align__(16) u16 lsP[2][WQ * KT];   // per-wave [qrow][key], 8B-grp ^= row&6

  const int tid = threadIdx.x;            // 0..127
  const int wave = tid >> 6, lane = tid & 63;
  const int lq = lane & 15, lr = lane >> 4;
  const int i = blockIdx.x;               // 0..1023
  const int xcd = i & 7, j = i >> 3;      // j: 0..127
  const int bh = xcd * 4 + (j >> 5);      // 4 heads per XCD
  const int q0 = (j & 31) * QT;
  const u16* Qg = qb + ((size_t)bh * SEQ + q0 + wave * WQ) * HD;
  const u16* Kg = kb + (size_t)bh * SEQ * HD;
  const u16* Vg = vbt + (size_t)bh * HD * SEQP;

  auto stage = [&](int tile, int buf) {
    const int k0 = tile * KT;
    #pragma unroll
    for (int ii = 0; ii < 4; ++ii) {
      int c = tid + ii * 128;
      int key = c >> 4, grp = c & 15;
      async16(Kg + (size_t)(k0 + key) * HD + ((grp ^ (key & 7)) * 8), lsK[buf] + c * 8);
    }
    #pragma unroll
    for (int ii = 0; ii < 4; ++ii) {
      int c = tid + ii * 128;
      int d = c >> 2, g2 = c & 3;
      async16(Vg + (size_t)d * SEQP + k0 + ((g2 ^ ((d >> 1) & 3)) * 8), lsV[buf] + c * 8);
    }
  };

  stage(0, 0);

  bf16x8 qf[2][4];
  #pragma unroll
  for (int qq = 0; qq < 2; ++qq)
    #pragma unroll
    for (int ks = 0; ks < 4; ++ks)
      qf[qq][ks] = *(const bf16x8*)(Qg + (size_t)(qq * 16 + lq) * HD + ks * 32 + lr * 8);

  f32x4 acc_o[2][8];
  float lsum[2] = {0.f, 0.f};
  #pragma unroll
  for (int mb = 0; mb < 2; ++mb)
    #pragma unroll
    for (int nb = 0; nb < 8; ++nb) acc_o[mb][nb] = f32x4{0.f, 0.f, 0.f, 0.f};

  for (int t = 0; t < NTILE; ++t) {
    const int p = t & 1;
    __syncthreads();                 // drains stage(t); all waves done with buf 1-p
    if (t + 1 < NTILE) stage(t + 1, 1 - p);

    // S^T = K Q^T : 32 keys x 32 q-rows per wave
    f32x4 sacc[2][2];
    #pragma unroll
    for (int kbi = 0; kbi < 2; ++kbi)
      #pragma unroll
      for (int qq = 0; qq < 2; ++qq) sacc[kbi][qq] = f32x4{0.f, 0.f, 0.f, 0.f};
    #pragma unroll
    for (int ks = 0; ks < 4; ++ks) {
      bf16x8 kf[2];
      #pragma unroll
      for (int kbi = 0; kbi < 2; ++kbi) {
        int key = kbi * 16 + lq;
        int g = (ks * 4 + lr) ^ (key & 7);
        kf[kbi] = *(const bf16x8*)(lsK[p] + key * HD + g * 8);
      }
      #pragma unroll
      for (int kbi = 0; kbi < 2; ++kbi)
        #pragma unroll
        for (int qq = 0; qq < 2; ++qq)
          sacc[kbi][qq] = __builtin_amdgcn_mfma_f32_16x16x32_bf16(kf[kbi], qf[qq][ks], sacc[kbi][qq], 0, 0, 0);
    }

    // P = exp2(S) (log2e folded into q); packed b64 writes (4 consecutive keys/lane)
    #pragma unroll
    for (int kbi = 0; kbi < 2; ++kbi)
      #pragma unroll
      for (int qq = 0; qq < 2; ++qq) {
        float p0 = __builtin_amdgcn_exp2f(sacc[kbi][qq][0]);
        float p1 = __builtin_amdgcn_exp2f(sacc[kbi][qq][1]);
        float p2 = __builtin_amdgcn_exp2f(sacc[kbi][qq][2]);
        float p3 = __builtin_amdgcn_exp2f(sacc[kbi][qq][3]);
        lsum[qq] += (p0 + p1) + (p2 + p3);
        int row = qq * 16 + lq;
        int g = kbi * 4 + lr;
        int gp = g ^ (row & 6);
        uint2 pk;
        pk.x = (uint32_t)f2bf(p0) | ((uint32_t)f2bf(p1) << 16);
        pk.y = (uint32_t)f2bf(p2) | ((uint32_t)f2bf(p3) << 16);
        *(uint2*)(lsP[wave] + row * KT + gp * 4) = pk;
      }

    // O += P V
    bf16x8 ap[2];
    #pragma unroll
    for (int mb = 0; mb < 2; ++mb) {
      int row = mb * 16 + lq;
      int gp = (2 * lr) ^ (row & 6);
      ap[mb] = *(const bf16x8*)(lsP[wave] + row * KT + gp * 4);
    }
    #pragma unroll
    for (int nb = 0; nb < 8; ++nb) {
      int d = nb * 16 + lq;
      int g2 = lr ^ ((d >> 1) & 3);
      bf16x8 bv = *(const bf16x8*)(lsV[p] + d * KT + g2 * 8);
      #pragma unroll
      for (int mb = 0; mb < 2; ++mb)
        acc_o[mb][nb] = __builtin_amdgcn_mfma_f32_16x16x32_bf16(ap[mb], bv[0] == bv[0] ? bv : bv, acc_o[mb][nb], 0, 0, 0);
    }
  }

  float inv[2];
  #pragma unroll
  for (int qq = 0; qq < 2; ++qq) {
    float s = lsum[qq];
    s += __shfl_xor(s, 16);
    s += __shfl_xor(s, 32);
    inv[qq] = 1.0f / s;
  }
  const int b = bh >> 4, h = bh & 15;
  #pragma unroll
  for (int mb = 0; mb < 2; ++mb)
    #pragma unroll
    for (int r = 0; r < 4; ++r) {
      float iv = __shfl(inv[mb], lr * 4 + r);
      int row = wave * WQ + mb * 16 + lr * 4 + r;
      int sq = q0 + row;
      float* op = out + (((size_t)b * SEQ + sq) * NH + h) * HD;
      #pragma unroll
      for (int nb = 0; nb < 8; ++nb)
        op[nb * 16 + lq] = acc_o[mb][nb][r] * iv;
    }
}

// ---------------- launch ----------------

extern "C" void kernel_launch(void* const* d_in, const int* in_sizes, int n_in,
                              void* d_out, int out_size, void* d_ws, size_t ws_size,
                              hipStream_t stream) {
  (void)in_sizes; (void)n_in; (void)out_size; (void)ws_size;
  const float* x    = (const float*)d_in[0];
  const float* W    = (const float*)d_in[1];
  const float* bias = (const float*)d_in[2];
  float* out = (float*)d_out;

  char* p = (char*)d_ws;
  u16* xb  = (u16*)p;  p += (size_t)MM * EMB * 2;                     // 16.8 MB
  u16* wt  = (u16*)p;  p += (size_t)N3 * EMB * 2;                     // 25.2 MB
  u16* qb  = (u16*)p;  p += (size_t)NUM_B * NH * SEQ * HD * 2;        // 16.8 MB
  u16* kb  = (u16*)p;  p += (size_t)NUM_B * NH * SEQ * HD * 2;        // 16.8 MB
  u16* vbt = (u16*)p;  p += (size_t)NUM_B * NH * HD * SEQP * 2;       // 17.0 MB
  float2* tab = (float2*)p;                                           // 2.1 MB

  k_cvt_bf16<<<(MM * EMB / 4 + 255) / 256, 256, 0, stream>>>(x, xb, MM * EMB / 4);
  k_transpose_w<<<dim3(N3 / 32, EMB / 32), dim3(32, 8), 0, stream>>>(W, wt);
  k_sincos<<<(SEQ * HD) / 256, 256, 0, stream>>>(tab);
  k_gemm_qkv<<<dim3(N3 / BN, MM / BM), 512, 0, stream>>>(xb, wt, bias, tab, qb, kb, vbt);
  k_flash<<<SEQ / QT * NUM_B * NH, 128, 0, stream>>>(qb, kb, vbt, out);
}

// Round 8
// 252.868 us; speedup vs baseline: 1.5207x; 1.0011x over previous
//
#include <hip/hip_runtime.h>
#include <stdint.h>

typedef unsigned short u16;
typedef __attribute__((ext_vector_type(8))) short bf16x8;   // 8 bf16 = 4 VGPRs
typedef __attribute__((ext_vector_type(4))) float f32x4;

#define NUM_B 2
#define SEQ   2048
#define SEQP  2080      // padded V row stride
#define NH    16
#define HD    128
#define EMB   2048      // NH*HD
#define N3    6144      // 3*EMB
#define MM    4096      // NUM_B*SEQ
#define QT    64        // flash q-rows per block (2 waves)
#define WQ    32        // flash q-rows per wave
#define KT    32        // flash keys per k-tile
#define NTILE (SEQ / KT)

// ---- GEMM tile params: m201-geometry 256x256, BK=64, 8 waves ----
#define BM 256
#define BN 256
#define BK 64
#define NT_K (EMB / BK)   // 32 K-tiles, 16 iterations of 2

__device__ __forceinline__ u16 f2bf(float f) {
  union { float f; unsigned u; } c; c.f = f;
  return (u16)((c.u + 0x7FFFu + ((c.u >> 16) & 1u)) >> 16);   // RNE
}
__device__ __forceinline__ void async16(const void* g, void* l) {
  __builtin_amdgcn_global_load_lds(
      (const __attribute__((address_space(1))) void*)g,
      (__attribute__((address_space(3))) void*)l, 16, 0, 0);
}

#define GBAR()   asm volatile("s_barrier" ::: "memory")
#define WLGKM0() asm volatile("s_waitcnt lgkmcnt(0)" ::: "memory")

// ---------------- prep kernels ----------------

__global__ void k_cvt_bf16(const float* __restrict__ in, u16* __restrict__ out, int n4) {
  int i = blockIdx.x * blockDim.x + threadIdx.x;
  if (i >= n4) return;
  const float4 v = ((const float4*)in)[i];
  ushort4 o;
  o.x = f2bf(v.x); o.y = f2bf(v.y); o.z = f2bf(v.z); o.w = f2bf(v.w);
  ((ushort4*)out)[i] = o;
}

// W [EMB][N3] fp32 -> Wt [N3][EMB] bf16
__global__ void k_transpose_w(const float* __restrict__ W, u16* __restrict__ Wt) {
  __shared__ float t[32][33];
  int n0 = blockIdx.x * 32, k0 = blockIdx.y * 32;
  int tx = threadIdx.x, ty = threadIdx.y;
  #pragma unroll
  for (int i = ty; i < 32; i += 8)
    t[i][tx] = W[(size_t)(k0 + i) * N3 + n0 + tx];
  __syncthreads();
  #pragma unroll
  for (int i = ty; i < 32; i += 8)
    Wt[(size_t)(n0 + i) * EMB + k0 + tx] = f2bf(t[tx][i]);
}

// sincos table for t = s*HD + d; double-precision sincos matches numpy fp32 tables
__global__ void k_sincos(float2* __restrict__ tab) {
  int i = blockIdx.x * blockDim.x + threadIdx.x;   // 0 .. SEQ*HD-1
  double t = (double)i;
  tab[i] = make_float2((float)cos(t), (float)sin(t));
}

// ---------------- QKV GEMM: 256x256, 8 waves, balanced (kk,mh) 4-phase ----------------
// R6 post-mortem: 256x384 -> acc[8][6]=192 regs/wave -> scratch spill (WRITE
// 50->255 MB, 15% MfmaUtil). Constraint: per-wave acc <= 128 f32 -> back to
// the proven 256x256 / acc[8][4] geometry (R4: no spill, 134.8 us).
// R4's residual flaw: q0 phase bundled 12/24 ds_reads. Fix: phases keyed
// (kk, mh) -> reads 8/4/8/4 vs 16 MFMA each:
//   P0(kk0,mh0): bfr[4][kk0] + af[0-3][kk0] (8 rd)  P1(kk0,mh1): af[4-7][kk0] (4)
//   P2(kk1,mh0): bfr[4][kk1] + af[0-3][kk1] (8)     P3(kk1,mh1): af[4-7][kk1] (4)
// Per-element accumulation order kk0->kk1 unchanged -> bit-identical.
// Staging (2 K-tiles per iter; buf = t&1; 2 async16-calls per slot):
//   hp0: P0 stA(t1,0)  P1 stA(t1,1)  P3 stB(t0+2,0)+stB(t0+2,1) ; vmcnt(4)
//        (queue: B(t1)4 A(t1)4 B(t0+2)4 -> lands tile t1, keeps B(t0+2))
//   hp1: P0 stA(t0+2,0) P1 stA(t0+2,1) P3 stB(t1+2,0)+stB(t1+2,1) ; vmcnt(4)
//        (queue: B(t0+2)4 A(t0+2)4 B(t1+2)4 -> lands t0+2, keeps B(t1+2))
// B staged only at P3 (P2's bfr reads retired at P2's WLGKM0, before P2 end
// barrier -> no read/overwrite race; staging at P2 would race its own bfr).
// vmcnt never 0 except last pair. Phase: reads; stage; [lgkmcnt(4) if 8-rd];
// GBAR; lgkmcnt(0); setprio(1); 16 MFMA; setprio(0); GBAR.
// Swizzle (T2, 0-conflict R1-R6): slot quad = quad ^ (row&7) on per-lane
// GLOBAL source (LDS dest linear) + on ds_read quad; frag rows have
// row&7 == lq&7 so qsw[kk] = ((kk*4+lr)^(lq&7))*8.
// RoPE-pair N-remap (verified R4): wave wc, frag nf -> within-head
// d = (2*(wc&1)+(nf>>1))*16 + (nf&1)*64 + lq, head = wc>>1.
__global__ __launch_bounds__(512, 2) void k_gemm_qkv(
    const u16* __restrict__ xb, const u16* __restrict__ wt,
    const float* __restrict__ bias, const float2* __restrict__ tab,
    u16* __restrict__ qb, u16* __restrict__ kb, u16* __restrict__ vbt)
{
  __shared__ __align__(16) u16 lsA[2][BM * BK];   // 32 KB x2
  __shared__ __align__(16) u16 lsB[2][BN * BK];   // 32 KB x2  (128 KB total)
  const int tid = threadIdx.x;            // 0..511
  const int wave = tid >> 6, lane = tid & 63;
  const int lq = lane & 15, lr = lane >> 4;
  const int wr = wave >> 2, wc = wave & 3;
  const int m0 = blockIdx.y * BM, n0 = blockIdx.x * BN;

  auto stA = [&](int t, int half) {       // one half-tile: 2 loads/thread, 16 KB
    const int kt = t * BK;
    #pragma unroll
    for (int ii = 0; ii < 2; ++ii) {
      int s = ii * 512 + tid;             // 16B slot 0..1023 within half
      int row = s >> 3, gq = (s & 7) ^ (row & 7);
      async16(xb + (size_t)(m0 + half * 128 + row) * EMB + kt + gq * 8,
              &lsA[t & 1][half * 8192 + s * 8]);
    }
  };
  auto stB = [&](int t, int half) {
    const int kt = t * BK;
    #pragma unroll
    for (int ii = 0; ii < 2; ++ii) {
      int s = ii * 512 + tid;
      int row = s >> 3, gq = (s & 7) ^ (row & 7);
      async16(wt + (size_t)(n0 + half * 128 + row) * EMB + kt + gq * 8,
              &lsB[t & 1][half * 8192 + s * 8]);
    }
  };

  f32x4 acc[8][4];
  #pragma unroll
  for (int i = 0; i < 8; ++i)
    #pragma unroll
    for (int j = 0; j < 4; ++j)
      acc[i][j] = f32x4{0.f, 0.f, 0.f, 0.f};

  // per-lane LDS read offsets (u16 units)
  int rbase[4];
  #pragma unroll
  for (int nf = 0; nf < 4; ++nf)
    rbase[nf] = ((wc >> 1) * 128 + (2 * (wc & 1) + (nf >> 1)) * 16 + (nf & 1) * 64 + lq) * BK;
  const int aRow0 = (wr * 128 + lq) * BK;
  int qsw[2];
  qsw[0] = ((0 + lr) ^ (lq & 7)) * 8;
  qsw[1] = ((4 + lr) ^ (lq & 7)) * 8;

  // prologue: A(0) B(0) B(1) = 12 loads; vmcnt(4) -> A(0)+B(0) landed, B(1) in flight
  stA(0, 0); stA(0, 1); stB(0, 0); stB(0, 1); stB(1, 0); stB(1, 1);
  asm volatile("s_waitcnt vmcnt(4)" ::: "memory");
  GBAR();

  for (int ti = 0; ti < NT_K / 2; ++ti) {
    const int t0 = 2 * ti, t1 = t0 + 1;
    const bool nl = (ti < NT_K / 2 - 1);

    #pragma unroll
    for (int hp = 0; hp < 2; ++hp) {      // hp=0: tile t0 (buf0), hp=1: t1 (buf1)
      const u16* Ap = lsA[hp];
      const u16* Bp = lsB[hp];

      #pragma unroll
      for (int p = 0; p < 4; ++p) {
        const int kk = p >> 1, mh = p & 1;
        // ---- ds_read register subtiles ----
        bf16x8 bfr[4];
        if (mh == 0) {
          #pragma unroll
          for (int nf = 0; nf < 4; ++nf)
            bfr[nf] = *(const bf16x8*)(Bp + rbase[nf] + qsw[kk]);
        }
        bf16x8 af[4];
        #pragma unroll
        for (int m4 = 0; m4 < 4; ++m4)
          af[m4] = *(const bf16x8*)(Ap + aRow0 + ((mh * 4 + m4) * 16) * BK + qsw[kk]);

        // ---- stage schedule (A at P0/P1, B bunched at P3, counted vmcnt) ----
        if (hp == 0) {
          if      (p == 0) stA(t1, 0);
          else if (p == 1) stA(t1, 1);
          else if (p == 3) {
            if (nl) {
              stB(t0 + 2, 0); stB(t0 + 2, 1);
              asm volatile("s_waitcnt vmcnt(4)" ::: "memory");  // lands A(t1)+B(t1)
            } else {
              asm volatile("s_waitcnt vmcnt(0)" ::: "memory");  // drain for final tile
            }
          }
        } else {
          if (nl) {
            if      (p == 0) stA(t0 + 2, 0);
            else if (p == 1) stA(t0 + 2, 1);
            else if (p == 3) {
              stB(t1 + 2, 0); stB(t1 + 2, 1);
              asm volatile("s_waitcnt vmcnt(4)" ::: "memory");  // lands tile t0+2
            }
          }
        }
        if (mh == 0) asm volatile("s_waitcnt lgkmcnt(4)" ::: "memory");  // partial drain, 8-read phase

        GBAR();
        WLGKM0();
        __builtin_amdgcn_s_setprio(1);
        // bfr persists across the mh==1 phase in regs (read at mh==0 of this kk)
        static bf16x8 bfr_keep[4];  // (never used; placeholder comment-free)
        (void)bfr_keep;
        #pragma unroll
        for (int m4 = 0; m4 < 4; ++m4)
          #pragma unroll
          for (int nf = 0; nf < 4; ++nf)
            acc[mh * 4 + m4][nf] = __builtin_amdgcn_mfma_f32_16x16x32_bf16(
                af[m4], bfr[nf], acc[mh * 4 + m4][nf], 0, 0, 0);
        __builtin_amdgcn_s_setprio(0);
        GBAR();
      }
    }
  }

  // ---------------- epilogue (fused bias + RoPE / V-transpose; verified R4) ----------------
  const int w = n0 >> 11;                  // 0=q, 1=k, 2=v (BN=256 divides 2048)
  const int h = ((n0 & 2047) >> 7) + (wc >> 1);
  float bb[4];
  int dloc[4];
  #pragma unroll
  for (int nf = 0; nf < 4; ++nf) {
    dloc[nf] = (2 * (wc & 1) + (nf >> 1)) * 16 + (nf & 1) * 64 + lq;   // d within head
    bb[nf] = bias[n0 + (wc >> 1) * 128 + dloc[nf]];
  }

  if (w == 2) {
    // V: transpose to [B,H,D,SEQP], 4 consecutive s per 8B store
    #pragma unroll
    for (int mf = 0; mf < 8; ++mf) {
      int mg0 = m0 + wr * 128 + mf * 16 + lr * 4;
      int b = mg0 >> 11, s0 = mg0 & 2047;
      #pragma unroll
      for (int nf = 0; nf < 4; ++nf) {
        int d = dloc[nf];
        ushort4 pk;
        pk.x = f2bf(acc[mf][nf][0] + bb[nf]);
        pk.y = f2bf(acc[mf][nf][1] + bb[nf]);
        pk.z = f2bf(acc[mf][nf][2] + bb[nf]);
        pk.w = f2bf(acc[mf][nf][3] + bb[nf]);
        *(ushort4*)(vbt + ((size_t)(b * NH + h) * HD + d) * SEQP + s0) = pk;
      }
    }
  } else {
    u16* basep = (w == 0) ? qb : kb;
    const float qs = (w == 0) ? 0.12751569843736827f : 1.0f;  // log2(e)/sqrt(128) into q
    #pragma unroll
    for (int mf = 0; mf < 8; ++mf)
      #pragma unroll
      for (int r = 0; r < 4; ++r) {
        int mg = m0 + wr * 128 + mf * 16 + lr * 4 + r;
        int b = mg >> 11, s = mg & 2047;
        u16* dst = basep + ((size_t)(b * NH + h) * SEQ + s) * HD;
        #pragma unroll
        for (int pl = 0; pl < 2; ++pl) {
          int d1 = (2 * (wc & 1) + pl) * 16 + lq;      // in [0,64); partner d1+64
          float c1 = acc[mf][2 * pl][r]     + bb[2 * pl];
          float c2 = acc[mf][2 * pl + 1][r] + bb[2 * pl + 1];
          float2 s1 = tab[s * HD + d1];
          float2 s2 = tab[s * HD + d1 + 64];
          dst[d1]      = f2bf((c1 * s1.x - c2 * s1.y) * qs);
          dst[d1 + 64] = f2bf((c2 * s2.x + c1 * s2.y) * qs);
        }
      }
  }
}

// ---------------- flash attention (unchanged; round-4 structure + XCD-aware remap) ----------------
__global__ __launch_bounds__(128, 2) void k_flash(
    const u16* __restrict__ qb, const u16* __restrict__ kb,
    const u16* __restrict__ vbt, float* __restrict__ out)
{
  __shared__ __align__(16) u16 lsK[2][KT * HD];   // [key][d] 16B-grp ^= key&7    (8 KB x2)
  __shared__ __align__(16) u16 lsV[2][HD * KT];   // [d][key] 16B-grp ^= (d>>1)&3 (8 KB x2)
  __shared__ __align__(16) u16 lsP[2][WQ * KT];   // per-wave [qrow][key], 8B-grp ^= row&6

  const int tid = threadIdx.x;            // 0..127
  const int wave = tid >> 6, lane = tid & 63;
  const int lq = lane & 15, lr = lane >> 4;
  const int i = blockIdx.x;               // 0..1023
  const int xcd = i & 7, j = i >> 3;      // j: 0..127
  const int bh = xcd * 4 + (j >> 5);      // 4 heads per XCD
  const int q0 = (j & 31) * QT;
  const u16* Qg = qb + ((size_t)bh * SEQ + q0 + wave * WQ) * HD;
  const u16* Kg = kb + (size_t)bh * SEQ * HD;
  const u16* Vg = vbt + (size_t)bh * HD * SEQP;

  auto stage = [&](int tile, int buf) {
    const int k0 = tile * KT;
    #pragma unroll
    for (int ii = 0; ii < 4; ++ii) {
      int c = tid + ii * 128;
      int key = c >> 4, grp = c & 15;
      async16(Kg + (size_t)(k0 + key) * HD + ((grp ^ (key & 7)) * 8), lsK[buf] + c * 8);
    }
    #pragma unroll
    for (int ii = 0; ii < 4; ++ii) {
      int c = tid + ii * 128;
      int d = c >> 2, g2 = c & 3;
      async16(Vg + (size_t)d * SEQP + k0 + ((g2 ^ ((d >> 1) & 3)) * 8), lsV[buf] + c * 8);
    }
  };

  stage(0, 0);

  bf16x8 qf[2][4];
  #pragma unroll
  for (int qq = 0; qq < 2; ++qq)
    #pragma unroll
    for (int ks = 0; ks < 4; ++ks)
      qf[qq][ks] = *(const bf16x8*)(Qg + (size_t)(qq * 16 + lq) * HD + ks * 32 + lr * 8);

  f32x4 acc_o[2][8];
  float lsum[2] = {0.f, 0.f};
  #pragma unroll
  for (int mb = 0; mb < 2; ++mb)
    #pragma unroll
    for (int nb = 0; nb < 8; ++nb) acc_o[mb][nb] = f32x4{0.f, 0.f, 0.f, 0.f};

  for (int t = 0; t < NTILE; ++t) {
    const int p = t & 1;
    __syncthreads();                 // drains stage(t); all waves done with buf 1-p
    if (t + 1 < NTILE) stage(t + 1, 1 - p);

    // S^T = K Q^T : 32 keys x 32 q-rows per wave
    f32x4 sacc[2][2];
    #pragma unroll
    for (int kbi = 0; kbi < 2; ++kbi)
      #pragma unroll
      for (int qq = 0; qq < 2; ++qq) sacc[kbi][qq] = f32x4{0.f, 0.f, 0.f, 0.f};
    #pragma unroll
    for (int ks = 0; ks < 4; ++ks) {
      bf16x8 kf[2];
      #pragma unroll
      for (int kbi = 0; kbi < 2; ++kbi) {
        int key = kbi * 16 + lq;
        int g = (ks * 4 + lr) ^ (key & 7);
        kf[kbi] = *(const bf16x8*)(lsK[p] + key * HD + g * 8);
      }
      #pragma unroll
      for (int kbi = 0; kbi < 2; ++kbi)
        #pragma unroll
        for (int qq = 0; qq < 2; ++qq)
          sacc[kbi][qq] = __builtin_amdgcn_mfma_f32_16x16x32_bf16(kf[kbi], qf[qq][ks], sacc[kbi][qq], 0, 0, 0);
    }

    // P = exp2(S) (log2e folded into q); packed b64 writes (4 consecutive keys/lane)
    #pragma unroll
    for (int kbi = 0; kbi < 2; ++kbi)
      #pragma unroll
      for (int qq = 0; qq < 2; ++qq) {
        float p0 = __builtin_amdgcn_exp2f(sacc[kbi][qq][0]);
        float p1 = __builtin_amdgcn_exp2f(sacc[kbi][qq][1]);
        float p2 = __builtin_amdgcn_exp2f(sacc[kbi][qq][2]);
        float p3 = __builtin_amdgcn_exp2f(sacc[kbi][qq][3]);
        lsum[qq] += (p0 + p1) + (p2 + p3);
        int row = qq * 16 + lq;
        int g = kbi * 4 + lr;
        int gp = g ^ (row & 6);
        uint2 pk;
        pk.x = (uint32_t)f2bf(p0) | ((uint32_t)f2bf(p1) << 16);
        pk.y = (uint32_t)f2bf(p2) | ((uint32_t)f2bf(p3) << 16);
        *(uint2*)(lsP[wave] + row * KT + gp * 4) = pk;
      }

    // O += P V
    bf16x8 ap[2];
    #pragma unroll
    for (int mb = 0; mb < 2; ++mb) {
      int row = mb * 16 + lq;
      int gp = (2 * lr) ^ (row & 6);
      ap[mb] = *(const bf16x8*)(lsP[wave] + row * KT + gp * 4);
    }
    #pragma unroll
    for (int nb = 0; nb < 8; ++nb) {
      int d = nb * 16 + lq;
      int g2 = lr ^ ((d >> 1) & 3);
      bf16x8 bv = *(const bf16x8*)(lsV[p] + d * KT + g2 * 8);
      #pragma unroll
      for (int mb = 0; mb < 2; ++mb)
        acc_o[mb][nb] = __builtin_amdgcn_mfma_f32_16x16x32_bf16(ap[mb], bv[0] == bv[0] ? bv : bv, acc_o[mb][nb], 0, 0, 0);
    }
  }

  float inv[2];
  #pragma unroll
  for (int qq = 0; qq < 2; ++qq) {
    float s = lsum[qq];
    s += __shfl_xor(s, 16);
    s += __shfl_xor(s, 32);
    inv[qq] = 1.0f / s;
  }
  const int b = bh >> 4, h = bh & 15;
  #pragma unroll
  for (int mb = 0; mb < 2; ++mb)
    #pragma unroll
    for (int r = 0; r < 4; ++r) {
      float iv = __shfl(inv[mb], lr * 4 + r);
      int row = wave * WQ + mb * 16 + lr * 4 + r;
      int sq = q0 + row;
      float* op = out + (((size_t)b * SEQ + sq) * NH + h) * HD;
      #pragma unroll
      for (int nb = 0; nb < 8; ++nb)
        op[nb * 16 + lq] = acc_o[mb][nb][r] * iv;
    }
}

// ---------------- launch ----------------

extern "C" void kernel_launch(void* const* d_in, const int* in_sizes, int n_in,
                              void* d_out, int out_size, void* d_ws, size_t ws_size,
                              hipStream_t stream) {
  (void)in_sizes; (void)n_in; (void)out_size; (void)ws_size;
  const float* x    = (const float*)d_in[0];
  const float* W    = (const float*)d_in[1];
  const float* bias = (const float*)d_in[2];
  float* out = (float*)d_out;

  char* p = (char*)d_ws;
  u16* xb  = (u16*)p;  p += (size_t)MM * EMB * 2;                     // 16.8 MB
  u16* wt  = (u16*)p;  p += (size_t)N3 * EMB * 2;                     // 25.2 MB
  u16* qb  = (u16*)p;  p += (size_t)NUM_B * NH * SEQ * HD * 2;        // 16.8 MB
  u16* kb  = (u16*)p;  p += (size_t)NUM_B * NH * SEQ * HD * 2;        // 16.8 MB
  u16* vbt = (u16*)p;  p += (size_t)NUM_B * NH * HD * SEQP * 2;       // 17.0 MB
  float2* tab = (float2*)p;                                           // 2.1 MB

  k_cvt_bf16<<<(MM * EMB / 4 + 255) / 256, 256, 0, stream>>>(x, xb, MM * EMB / 4);
  k_transpose_w<<<dim3(N3 / 32, EMB / 32), dim3(32, 8), 0, stream>>>(W, wt);
  k_sincos<<<(SEQ * HD) / 256, 256, 0, stream>>>(tab);
  k_gemm_qkv<<<dim3(N3 / BN, MM / BM), 512, 0, stream>>>(xb, wt, bias, tab, qb, kb, vbt);
  k_flash<<<SEQ / QT * NUM_B * NH, 128, 0, stream>>>(qb, kb, vbt, out);
}